// Round 13
// baseline (777.403 us; speedup 1.0000x reference)
//
#include <hip/hip_runtime.h>
#include <math.h>

// ---------------------------------------------------------------------------
// out = (silu(x) @ (W/sigma)^T + b  +  softthr(basis(x) @ Ww^T)) * oscale
// Producer/consumer fused GEMM, merged K = [kan 7168 | base 1024] = 8192.
// BM=256 x BN=128, BK=64. 8 waves: 4 consumers (2Mx2N, 128x64 wave tiles,
// MFMA 16x16x32) + 4 producers (compute basis/silu from x, write A-tiles to
// LDS). 2 LDS buffers, 1 barrier/tile. Kan K is i-chunk-major (t = ic*7+g) so
// producers load each x-chunk once per 7 tiles. No A' in HBM, no chunking.
// softthr in-register at the kan/base boundary (tile 112).
// ---------------------------------------------------------------------------

typedef __attribute__((ext_vector_type(4))) float  f32x4;
typedef __attribute__((ext_vector_type(8))) __bf16 bf16x8;
typedef __attribute__((ext_vector_type(8))) unsigned short u16x8;
typedef __attribute__((ext_vector_type(4))) unsigned int u32x4;

#define NROWS 16384
#define INF   1024
#define OUTF  1024
#define GG    7
#define KKAN  7168
#define KTOT  8192

static __device__ __forceinline__ unsigned short f2bf(float f) {
  union { float f; unsigned int u; } v; v.f = f;
  unsigned int r = v.u + 0x7fffu + ((v.u >> 16) & 1u);  // RNE
  return (unsigned short)(r >> 16);
}

// ---------------- sigma (spectral norm) ----------------
__global__ void zero_t(float* __restrict__ t) { t[threadIdx.x] = 0.f; }

__global__ void wtu_acc(const float* __restrict__ W, const float* __restrict__ u,
                        float* __restrict__ t) {
  int tid = threadIdx.x;
  int j4 = tid * 4;
  int i0 = blockIdx.x * 16;
  f32x4 acc = {0.f, 0.f, 0.f, 0.f};
  for (int i = i0; i < i0 + 16; ++i) {
    float ui = u[i];
    f32x4 w4 = *(const f32x4*)(W + (size_t)i * INF + j4);
    acc[0] += w4[0] * ui; acc[1] += w4[1] * ui;
    acc[2] += w4[2] * ui; acc[3] += w4[3] * ui;
  }
  atomicAdd(&t[j4 + 0], acc[0]);
  atomicAdd(&t[j4 + 1], acc[1]);
  atomicAdd(&t[j4 + 2], acc[2]);
  atomicAdd(&t[j4 + 3], acc[3]);
}

__global__ void mv_w_t(const float* __restrict__ W, const float* __restrict__ t,
                       float* __restrict__ s) {
  int i = blockIdx.x;
  int tid = threadIdx.x;
  float p = 0.f;
  for (int j = tid; j < INF; j += 256) p += W[(size_t)i * INF + j] * t[j];
  __shared__ float red[256];
  red[tid] = p; __syncthreads();
  for (int k = 128; k > 0; k >>= 1) { if (tid < k) red[tid] += red[tid + k]; __syncthreads(); }
  if (tid == 0) s[i] = red[0];
}

__global__ void sigma_finish(const float* __restrict__ t, const float* __restrict__ s,
                             const float* __restrict__ st, const float* __restrict__ os,
                             float* __restrict__ scal) {
  __shared__ float r1[256], r2[256];
  int tid = threadIdx.x;
  float p1 = 0.f, p2 = 0.f;
  for (int i = tid; i < 1024; i += 256) { float a = t[i]; p1 += a * a; float b = s[i]; p2 += b * b; }
  r1[tid] = p1; r2[tid] = p2; __syncthreads();
  for (int k = 128; k > 0; k >>= 1) { if (tid < k) { r1[tid] += r1[tid + k]; r2[tid] += r2[tid + k]; } __syncthreads(); }
  if (tid == 0) {
    float nt = sqrtf(r1[0]);
    float ns = sqrtf(r2[0]);
    float nq = ns / (nt + 1e-12f);
    float sigma = nq * nq / (nq + 1e-12f);
    scal[0] = 1.f / sigma;
    scal[1] = log1pf(__expf(st[0]));
    scal[2] = os[0];
  }
}

// ---------------- weight casts into W' [1024][8192] ----------------
__global__ void wsn_cast(const float* __restrict__ w, const float* __restrict__ scal,
                         unsigned short* __restrict__ Wp) {
  float is = scal[0];
  int idx = blockIdx.x * 256 + threadIdx.x;
  int row = idx >> 7, i0 = (idx & 127) << 3;
  const f32x4* p = (const f32x4*)(w + (size_t)row * INF + i0);
  f32x4 a = p[0], b = p[1];
  u16x8 v;
  v[0] = f2bf(a[0] * is); v[1] = f2bf(a[1] * is); v[2] = f2bf(a[2] * is); v[3] = f2bf(a[3] * is);
  v[4] = f2bf(b[0] * is); v[5] = f2bf(b[1] * is); v[6] = f2bf(b[2] * is); v[7] = f2bf(b[3] * is);
  *(u16x8*)(Wp + (size_t)row * KTOT + KKAN + i0) = v;
}

// wavelet_w [o][i*7+g] -> Wp[o][ ((i>>6)*7 + g)*64 + (i&63) ]  (i-chunk major)
__global__ void wkan_cast(const float* __restrict__ w, unsigned short* __restrict__ Wp) {
  __shared__ float row[KKAN];
  int orow = blockIdx.x;
  const float* src = w + (size_t)orow * KKAN;
  for (int c = threadIdx.x * 4; c < KKAN; c += 1024)
    *(f32x4*)&row[c] = *(const f32x4*)&src[c];
  __syncthreads();
  unsigned short* dst = Wp + (size_t)orow * KTOT;
  for (int r = threadIdx.x; r < 896; r += 256) {
    int g = r >> 7, i0 = (r & 127) << 3;
    u16x8 v;
#pragma unroll
    for (int j = 0; j < 8; j++) v[j] = f2bf(row[(i0 + j) * GG + g]);
    *(u16x8*)(dst + ((i0 >> 6) * 7 + g) * 64 + (i0 & 63)) = v;
  }
}

// ---------------- GEMM machinery ----------------
static __device__ __forceinline__ void gload16(const unsigned short* g, unsigned short* l) {
  __builtin_amdgcn_global_load_lds(
      (const __attribute__((address_space(1))) unsigned int*)g,
      (__attribute__((address_space(3))) unsigned int*)l, 16, 0, 0);
}

#define SCB   __builtin_amdgcn_sched_barrier(0)
#define SBAR  do { SCB; __builtin_amdgcn_s_barrier(); } while (0)
#define VM(N) asm volatile("s_waitcnt vmcnt(" #N ")" ::: "memory")
#define LG(N) asm volatile("s_waitcnt lgkmcnt(" #N ")" ::: "memory")

// consumer: stage B-tile (128 rows x 64 k) of K-tile tt into buf bb (4 gloads)
#define BGLOAD(bb, tt) do { \
    const unsigned short* _s = gB + (size_t)(tt) * 64; \
    unsigned short* _d = lds + (bb) * 24576 + 16384 + wv * 512; \
    _Pragma("unroll") for (int r_ = 0; r_ < 4; ++r_) \
      gload16(_s + (size_t)(r_ * 32) * KTOT, _d + r_ * 2048); \
  } while (0)

// consumer: read one k-half's frags: A 8 (128 rows) + B 4 (64 cols)
#define RD12(kx, bb) do { \
    _Pragma("unroll") for (int i = 0; i < 8; ++i) \
      FA[i] = *(const bf16x8*)(pA + (bb) * 49152 + i * 2048 + (kx)); \
    _Pragma("unroll") for (int j = 0; j < 4; ++j) \
      FB[j] = *(const bf16x8*)(pB + (bb) * 49152 + j * 2048 + (kx)); \
  } while (0)

#define MM32 do { _Pragma("unroll") for (int i = 0; i < 8; ++i) \
    _Pragma("unroll") for (int j = 0; j < 4; ++j) \
      acc[i][j] = __builtin_amdgcn_mfma_f32_16x16x32_bf16(FA[i], FB[j], acc[i][j], 0, 0, 0); } while (0)

// producer: load x chunk (64 cols at ICOL) for its 8 rows; optional tanh
#define XLOADP(ICOL, TANH) do { \
    _Pragma("unroll") for (int w_ = 0; w_ < 8; ++w_) { \
      const f32x4* _p = (const f32x4*)(xbase + (size_t)(prow + w_ * 32) * 1024 + (ICOL) + pc * 8); \
      xd[w_][0] = _p[0]; xd[w_][1] = _p[1]; \
    } \
    if (TANH) { \
      _Pragma("unroll") for (int w_ = 0; w_ < 8; ++w_) \
      _Pragma("unroll") for (int h_ = 0; h_ < 2; ++h_) \
      _Pragma("unroll") for (int e_ = 0; e_ < 4; ++e_) { \
        float v_ = xd[w_][h_][e_]; \
        float e2_ = __expf(2.f * v_); \
        xd[w_][h_][e_] = 2.5f * (1.f - 2.f / (e2_ + 1.f)); \
      } \
    } \
  } while (0)

// producer: compute 64 values (basis or silu) and write XOR-swizzled A-tile
#define CWPROD(bb, IS_, NT_, SILU) do { \
    unsigned short* _wb = lds + (bb) * 24576; \
    _Pragma("unroll") for (int w_ = 0; w_ < 8; ++w_) { \
      int row_ = prow + w_ * 32; \
      float bv[8]; \
      _Pragma("unroll") for (int e_ = 0; e_ < 8; ++e_) { \
        float v_ = (e_ < 4) ? xd[w_][0][e_] : xd[w_][1][e_ - 4]; \
        if (SILU) { bv[e_] = v_ / (1.f + __expf(-v_)); } \
        else { float xe_ = fmaf(v_, IS_, NT_); float t2_ = xe_ * xe_; \
               bv[e_] = (1.f - t2_) * __expf(-0.5f * t2_); } \
      } \
      unsigned int o0, o1, o2, o3; \
      asm("v_cvt_pk_bf16_f32 %0, %1, %2" : "=v"(o0) : "v"(bv[0]), "v"(bv[1])); \
      asm("v_cvt_pk_bf16_f32 %0, %1, %2" : "=v"(o1) : "v"(bv[2]), "v"(bv[3])); \
      asm("v_cvt_pk_bf16_f32 %0, %1, %2" : "=v"(o2) : "v"(bv[4]), "v"(bv[5])); \
      asm("v_cvt_pk_bf16_f32 %0, %1, %2" : "=v"(o3) : "v"(bv[6]), "v"(bv[7])); \
      u32x4 w4_ = {o0, o1, o2, o3}; \
      *(u32x4*)(_wb + row_ * 64 + ((pc ^ (row_ & 7)) << 3)) = w4_; \
    } \
  } while (0)

// BM=256 x BN=128; waves 0-3 consume (MFMA), waves 4-7 produce (A-tiles)
__global__ __launch_bounds__(512, 2) void gemm_k(
    const float* __restrict__ x,            // [16384][1024] f32
    const unsigned short* __restrict__ W,   // [1024][8192] bf16
    const float* __restrict__ bias,
    const float* __restrict__ scal,
    const float* __restrict__ trP,          // translation [7]
    const float* __restrict__ scP,          // scale [7]
    float* __restrict__ out) {              // [16384][1024] f32
  __shared__ unsigned short lds[49184];     // 2 x 48KB (A 32K | B 16K) + table
  float* ldsF = (float*)(lds + 49152);

  int bid = blockIdx.x;
  int swz = (bid & 7) * 64 + (bid >> 3);    // XCD k owns n-panel k (B L2-hot)
  int n0 = (swz >> 6) * 128;
  int m0 = (swz & 63) * 256;
  int tid = threadIdx.x;
  int wv = tid >> 6, l = tid & 63;
  bool cons = wv < 4;
  int wr = (wv >> 1) & 1, wc = wv & 1;      // consumer 2M x 2N, 128x64 tiles

  float thr = scal[1], osc = scal[2];

  // consumer B staging (threads 0..255): row (tid>>3), pre-swizzled chunk
  int rowqB = tid >> 3;                     // 0..31 for consumers
  int swkB = ((tid & 7) ^ (rowqB & 7)) << 3;
  const unsigned short* gB = W + (size_t)(n0 + (rowqB & 31)) * KTOT + swkB;

  // consumer frag reads
  int lr = l & 15;
  int kx0 = (((l >> 4) << 4) ^ ((l & 7) << 4));
  int kx1 = kx0 ^ 64;
  const char* pA = (const char*)lds + (wr * 128 + lr) * 128;
  const char* pB = (const char*)lds + 32768 + (wc * 64 + lr) * 128;

  // producer addressing (threads 256..511)
  int pt = tid & 255;
  int prow = pt >> 3;                       // 0..31 (+32/w)
  int pc = pt & 7;                          // 16B chunk
  const float* xbase = x + (size_t)m0 * 1024;

  bf16x8 FA[8], FB[4];
  f32x4 xd[8][2];
  f32x4 acc[8][4] = {};

  // g-scalar table: iss[g], -tr[g]*iss[g]
  if (tid < 7) {
    float s = fabsf(scP[tid]);
    s = s < 0.1f ? 0.1f : s;
    ldsF[tid] = 1.f / s;
    ldsF[7 + tid] = -trP[tid] / s;
  }
  __syncthreads();

  // pre-loop: producers build tile 0 (buf0 A); consumers stage B(0) (buf0 B)
  if (cons) {
    BGLOAD(0, 0);
    VM(0);
  } else {
    XLOADP(0, 1);
    CWPROD(0, ldsF[0], ldsF[7], 0);
    LG(0);
  }
  SBAR;

  int pg = 1, picol = 0;                    // producer's next kan tile state

#pragma unroll 2
  for (int t = 0; t < 128; ++t) {
    int b = t & 1;
    if (cons) {
      RD12(kx0, b);
      if (t < 127) BGLOAD(b ^ 1, t + 1);
      LG(0); SCB;
      __builtin_amdgcn_s_setprio(1); MM32; __builtin_amdgcn_s_setprio(0);
      RD12(kx1, b);
      LG(0); SCB;
      __builtin_amdgcn_s_setprio(1); MM32; __builtin_amdgcn_s_setprio(0);
      if (t < 127) VM(0);
      SBAR;
      if (t == 111) {
        // soft-threshold at the kan/base boundary
#pragma unroll
        for (int i = 0; i < 8; ++i)
#pragma unroll
          for (int j = 0; j < 4; ++j)
#pragma unroll
            for (int e = 0; e < 4; ++e) {
              float v = acc[i][j][e];
              float a = fabsf(v) - thr;
              a = a > 0.f ? a : 0.f;
              acc[i][j][e] = v > 0.f ? a : -a;
            }
      }
    } else {
      if (t < 111) {                        // next tile t+1 is kan (ic, pg)
        if (pg == 0) XLOADP(picol, 1);
        float is_ = ldsF[pg], nt_ = ldsF[7 + pg];
        CWPROD(b ^ 1, is_, nt_, 0);
        pg = (pg == 6) ? 0 : pg + 1;
        if (pg == 0) picol += 64;
      } else if (t < 127) {                 // next tile is base (silu)
        XLOADP((t - 111) * 64, 0);
        CWPROD(b ^ 1, 0.f, 0.f, 1);
      }
      LG(0);
      SBAR;
    }
  }

  // epilogue: consumers write out = (acc + bias) * oscale
  if (cons) {
    int rr = m0 + wr * 128 + ((l >> 4) << 2);
    int cc = n0 + wc * 64 + lr;
#pragma unroll
    for (int i = 0; i < 8; ++i)
#pragma unroll
      for (int j = 0; j < 4; ++j) {
        int c = cc + j * 16;
        float bc = bias[c];
#pragma unroll
        for (int e = 0; e < 4; ++e) {
          int r = rr + i * 16 + e;
          out[(size_t)r * OUTF + c] = (acc[i][j][e] + bc) * osc;
        }
      }
  }
}

// ---------------------------------------------------------------------------
extern "C" void kernel_launch(void* const* d_in, const int* in_sizes, int n_in,
                              void* d_out, int out_size, void* d_ws, size_t ws_size,
                              hipStream_t stream) {
  const float* x              = (const float*)d_in[0];
  const float* base_w         = (const float*)d_in[1];
  const float* base_b         = (const float*)d_in[2];
  const float* u              = (const float*)d_in[3];
  const float* translation    = (const float*)d_in[4];
  const float* scale          = (const float*)d_in[5];
  const float* wavelet_w      = (const float*)d_in[6];
  const float* soft_threshold = (const float*)d_in[7];
  const float* output_scale   = (const float*)d_in[8];
  float* out = (float*)d_out;

  char* ws = (char*)d_ws;
  float* t_vec = (float*)ws;                                 // 1024 f32
  float* s_vec = t_vec + 1024;                               // 1024 f32
  float* scal  = s_vec + 1024;                               // 32 f32
  unsigned short* Wp = (unsigned short*)(ws + 16384);        // 16 MB

  zero_t<<<1, 1024, 0, stream>>>(t_vec);
  wtu_acc<<<64, 256, 0, stream>>>(base_w, u, t_vec);
  mv_w_t<<<1024, 256, 0, stream>>>(base_w, t_vec, s_vec);
  sigma_finish<<<1, 256, 0, stream>>>(t_vec, s_vec, soft_threshold, output_scale, scal);
  wsn_cast<<<512, 256, 0, stream>>>(base_w, scal, Wp);
  wkan_cast<<<1024, 256, 0, stream>>>(wavelet_w, Wp);

  gemm_k<<<512, 512, 0, stream>>>(x, Wp, base_b, scal, translation, scale, out);
}

// Round 14
// 321.698 us; speedup vs baseline: 2.4166x; 2.4166x over previous
//
#include <hip/hip_runtime.h>
#include <math.h>

// ---------------------------------------------------------------------------
// out = (silu(x) @ (W/sigma)^T + b  +  softthr(basis(x) @ Ww^T)) * oscale
// Merged K = [kan 7168 | base 1024] = 8192, bf16 MFMA (16x16x32).
// GEMM = R8 (best verified): BM=256 x BN=128, BK=64, 8 waves (4Mx2N, 64x64),
// 3 LDS buffers, half-K register pipeline, 1 barrier + vmcnt(6)/tile,
// softthr in-register at tile 112. Dispatch chain consolidated:
// memset(t) -> prep_fused(wtu+wkan_cast+expand(c0)) -> mv_w_t -> sigma ->
// wsn_cast -> [gemm(ci); expand(c(i+1))] loop.
// ---------------------------------------------------------------------------

typedef __attribute__((ext_vector_type(4))) float  f32x4;
typedef __attribute__((ext_vector_type(8))) __bf16 bf16x8;
typedef __attribute__((ext_vector_type(8))) unsigned short u16x8;

#define NROWS 16384
#define INF   1024
#define OUTF  1024
#define GG    7
#define KKAN  7168
#define KTOT  8192

static __device__ __forceinline__ unsigned short f2bf(float f) {
  union { float f; unsigned int u; } v; v.f = f;
  unsigned int r = v.u + 0x7fffu + ((v.u >> 16) & 1u);  // RNE
  return (unsigned short)(r >> 16);
}

// ---------------- expansion device helper (shared by 2 kernels) ------------
static __device__ __forceinline__ void expand_units(
    const float* __restrict__ x, const float* __restrict__ translation,
    const float* __restrict__ scale, unsigned short* __restrict__ Ap,
    int row0, int nrows, int bid0, int nblocks) {
  float tr[GG], iss[GG];
#pragma unroll
  for (int g = 0; g < GG; g++) {
    tr[g] = translation[g];
    float s = fabsf(scale[g]);
    iss[g] = 1.f / (s < 0.1f ? 0.1f : s);
  }
  int units = nrows * (INF / 8);
  int stride = nblocks * 256;
  for (int uu = bid0 * 256 + (int)threadIdx.x; uu < units; uu += stride) {
    int nloc = uu >> 7;
    int i0 = (uu & 127) << 3;
    const f32x4* xp = (const f32x4*)(x + (size_t)(row0 + nloc) * INF + i0);
    f32x4 xa = xp[0], xb = xp[1];
    float xv[8] = {xa[0], xa[1], xa[2], xa[3], xb[0], xb[1], xb[2], xb[3]};
    u16x8 sb, kb[GG];
#pragma unroll
    for (int j = 0; j < 8; j++) {
      float xx = xv[j];
      float si = xx / (1.f + __expf(-xx));
      sb[j] = f2bf(si);
      float e2 = __expf(2.f * xx);
      float xn = 2.5f * (1.f - 2.f / (e2 + 1.f));
#pragma unroll
      for (int g = 0; g < GG; g++) {
        float xe = (xn - tr[g]) * iss[g];
        float t2 = xe * xe;
        float b = (1.f - t2) * __expf(-0.5f * t2);
        kb[g][j] = f2bf(b);
      }
    }
    unsigned short* rp = Ap + (size_t)nloc * KTOT;
    *(u16x8*)(rp + KKAN + i0) = sb;
#pragma unroll
    for (int g = 0; g < GG; g++) *(u16x8*)(rp + g * 1024 + i0) = kb[g];
  }
}

// ---------------- fused prep: wtu_acc | wkan_cast | expand(chunk0) ---------
// blocks [0,64): t += W^T u partial (atomic)   [needs t pre-zeroed]
// blocks [64,1088): wavelet_w row transpose-cast into Wp
// blocks [1088,3136): expansion of rows [0, nrows0)
__global__ void prep_fused(const float* __restrict__ W, const float* __restrict__ u,
                           float* __restrict__ t,
                           const float* __restrict__ wkan,
                           unsigned short* __restrict__ Wp,
                           const float* __restrict__ x,
                           const float* __restrict__ translation,
                           const float* __restrict__ scale,
                           unsigned short* __restrict__ Ap, int nrows0) {
  __shared__ float row[KKAN];
  int bid = blockIdx.x;
  int tid = threadIdx.x;
  if (bid < 64) {
    int j4 = tid * 4;
    int i0 = bid * 16;
    f32x4 acc = {0.f, 0.f, 0.f, 0.f};
    for (int i = i0; i < i0 + 16; ++i) {
      float ui = u[i];
      f32x4 w4 = *(const f32x4*)(W + (size_t)i * INF + j4);
      acc[0] += w4[0] * ui; acc[1] += w4[1] * ui;
      acc[2] += w4[2] * ui; acc[3] += w4[3] * ui;
    }
    atomicAdd(&t[j4 + 0], acc[0]);
    atomicAdd(&t[j4 + 1], acc[1]);
    atomicAdd(&t[j4 + 2], acc[2]);
    atomicAdd(&t[j4 + 3], acc[3]);
  } else if (bid < 1088) {
    int orow = bid - 64;
    const float* src = wkan + (size_t)orow * KKAN;
    for (int c = tid * 4; c < KKAN; c += 1024)
      *(f32x4*)&row[c] = *(const f32x4*)&src[c];
    __syncthreads();
    unsigned short* dst = Wp + (size_t)orow * KTOT;
    for (int r = tid; r < 896; r += 256) {
      int g = r >> 7, i0 = (r & 127) << 3;
      u16x8 v;
#pragma unroll
      for (int j = 0; j < 8; j++) v[j] = f2bf(row[(i0 + j) * GG + g]);
      *(u16x8*)(dst + g * 1024 + i0) = v;
    }
  } else {
    expand_units(x, translation, scale, Ap, 0, nrows0, bid - 1088, 2048);
  }
}

// ---------------- standalone expand (later chunks) ----------------
__global__ void expand_kernel(const float* __restrict__ x,
                              const float* __restrict__ translation,
                              const float* __restrict__ scale,
                              unsigned short* __restrict__ Ap,
                              int row0, int nrows) {
  expand_units(x, translation, scale, Ap, row0, nrows, blockIdx.x, gridDim.x);
}

// ---------------- sigma chain ----------------
__global__ void mv_w_t(const float* __restrict__ W, const float* __restrict__ t,
                       float* __restrict__ s) {
  int i = blockIdx.x;
  int tid = threadIdx.x;
  float p = 0.f;
  for (int j = tid; j < INF; j += 256) p += W[(size_t)i * INF + j] * t[j];
  __shared__ float red[256];
  red[tid] = p; __syncthreads();
  for (int k = 128; k > 0; k >>= 1) { if (tid < k) red[tid] += red[tid + k]; __syncthreads(); }
  if (tid == 0) s[i] = red[0];
}

__global__ void sigma_finish(const float* __restrict__ t, const float* __restrict__ s,
                             const float* __restrict__ st, const float* __restrict__ os,
                             float* __restrict__ scal) {
  __shared__ float r1[256], r2[256];
  int tid = threadIdx.x;
  float p1 = 0.f, p2 = 0.f;
  for (int i = tid; i < 1024; i += 256) { float a = t[i]; p1 += a * a; float b = s[i]; p2 += b * b; }
  r1[tid] = p1; r2[tid] = p2; __syncthreads();
  for (int k = 128; k > 0; k >>= 1) { if (tid < k) { r1[tid] += r1[tid + k]; r2[tid] += r2[tid + k]; } __syncthreads(); }
  if (tid == 0) {
    float nt = sqrtf(r1[0]);
    float ns = sqrtf(r2[0]);
    float nq = ns / (nt + 1e-12f);
    float sigma = nq * nq / (nq + 1e-12f);
    scal[0] = 1.f / sigma;
    scal[1] = log1pf(__expf(st[0]));
    scal[2] = os[0];
  }
}

__global__ void wsn_cast(const float* __restrict__ w, const float* __restrict__ scal,
                         unsigned short* __restrict__ Wp) {
  float is = scal[0];
  int idx = blockIdx.x * 256 + threadIdx.x;
  int row = idx >> 7, i0 = (idx & 127) << 3;
  const f32x4* p = (const f32x4*)(w + (size_t)row * INF + i0);
  f32x4 a = p[0], b = p[1];
  u16x8 v;
  v[0] = f2bf(a[0] * is); v[1] = f2bf(a[1] * is); v[2] = f2bf(a[2] * is); v[3] = f2bf(a[3] * is);
  v[4] = f2bf(b[0] * is); v[5] = f2bf(b[1] * is); v[6] = f2bf(b[2] * is); v[7] = f2bf(b[3] * is);
  *(u16x8*)(Wp + (size_t)row * KTOT + KKAN + i0) = v;
}

// ---------------- GEMM machinery (R8, verified 114.2 us) ----------------
static __device__ __forceinline__ void gload16(const unsigned short* g, unsigned short* l) {
  __builtin_amdgcn_global_load_lds(
      (const __attribute__((address_space(1))) unsigned int*)g,
      (__attribute__((address_space(3))) unsigned int*)l, 16, 0, 0);
}

#define SCB   __builtin_amdgcn_sched_barrier(0)
#define SBAR  do { SCB; __builtin_amdgcn_s_barrier(); } while (0)
#define VM(N) asm volatile("s_waitcnt vmcnt(" #N ")" ::: "memory")
#define LG(N) asm volatile("s_waitcnt lgkmcnt(" #N ")" ::: "memory")

// stage full K-tile tt into buffer db: A 256x64 (4 gloads) + B 128x64 (2)
#define STAGE(db, tt) do { \
    const unsigned short* _sa = gA + (size_t)(tt) * 64; \
    const unsigned short* _sb = gB + (size_t)(tt) * 64; \
    unsigned short* _da = ldsS + (db) * 24576; \
    unsigned short* _db2 = ldsS + (db) * 24576 + 16384; \
    gload16(_sa,                       _da); \
    gload16(_sa + (size_t)64  * KTOT,  _da + 4096); \
    gload16(_sa + (size_t)128 * KTOT,  _da + 8192); \
    gload16(_sa + (size_t)192 * KTOT,  _da + 12288); \
    gload16(_sb,                       _db2); \
    gload16(_sb + (size_t)64 * KTOT,   _db2 + 4096); \
  } while (0)

#define RD8(FA, FB, bb, kx) do { \
    _Pragma("unroll") for (int i = 0; i < 4; ++i) \
      FA[i] = *(const bf16x8*)(pA + (bb) * 49152 + i * 2048 + (kx)); \
    _Pragma("unroll") for (int j = 0; j < 4; ++j) \
      FB[j] = *(const bf16x8*)(pB + (bb) * 49152 + j * 2048 + (kx)); \
  } while (0)

#define MM16(FA, FB) do { _Pragma("unroll") for (int i = 0; i < 4; ++i) \
    _Pragma("unroll") for (int j = 0; j < 4; ++j) \
      acc[i][j] = __builtin_amdgcn_mfma_f32_16x16x32_bf16(FA[i], FB[j], acc[i][j], 0, 0, 0); } while (0)

// one K-tile, software-pipelined frags:
//  P1: read half2(t)->fY | stage(t+2) | MFMA(fX = half1(t)) | LG0 | W1 | SBAR
//  P2: read half1(t+1)->fX from buf nb | MFMA(fY) | LG0
#define TILE(tt, bb, nb, db, SS, NR, W1) do { \
    RD8(fYA, fYB, bb, kx1); \
    SCB; \
    if (SS) STAGE(db, (tt) + 2); \
    SCB; \
    __builtin_amdgcn_s_setprio(1); MM16(fXA, fXB); __builtin_amdgcn_s_setprio(0); \
    LG(0); SCB; \
    W1; \
    SBAR; \
    if (NR) { RD8(fXA, fXB, nb, kx0); SCB; } \
    __builtin_amdgcn_s_setprio(1); MM16(fYA, fYB); __builtin_amdgcn_s_setprio(0); \
    LG(0); SCB; \
  } while (0)

// BM=256 x BN=128, 8 waves (4M x 2N), K = 8192 merged, softthr at tile 112
__global__ __launch_bounds__(512, 2) void gemm_k(
    const unsigned short* __restrict__ A,   // [mt*256][8192] bf16
    const unsigned short* __restrict__ W,   // [1024][8192] bf16
    const float* __restrict__ bias,
    const float* __restrict__ scal,
    float* __restrict__ out) {              // [mt*256][1024]
  __shared__ unsigned short lds[73728];     // 3 buffers x 48 KB (A 32K | B 16K)

  int bid = blockIdx.x;
  int cpx = gridDim.x >> 3;                 // grid % 8 == 0 (mt*8)
  int swz = (bid & 7) * cpx + (bid >> 3);   // XCD-bijective; n-inner => A reuse
  int m0 = (swz >> 3) * 256;
  int n0 = (swz & 7) * 128;
  int tid = threadIdx.x;
  int wv = tid >> 6, l = tid & 63;
  int wr = wv >> 1, wc = wv & 1;            // 4M x 2N waves, 64x64 tiles

  float thr = scal[1], osc = scal[2];

  // staging: thread covers row (tid>>3) (+64/round), XOR-preswizzled 16B chunk
  int rowq = tid >> 3;
  int swk = ((tid & 7) ^ (rowq & 7)) << 3;
  const unsigned short* gA = A + (size_t)(m0 + rowq) * KTOT + swk;
  const unsigned short* gB = W + (size_t)(n0 + rowq) * KTOT + swk;
  unsigned short* ldsS = lds + wv * 512;    // wave-uniform dest base

  // frag reads (XOR on read side matches staging pre-swizzle)
  int lr = l & 15;
  int kb = (l >> 4) << 4;
  int xr = (l & 7) << 4;
  int kx0 = kb ^ xr;
  int kx1 = (64 | kb) ^ xr;
  const char* pA = (const char*)lds + (wr * 64 + lr) * 128;
  const char* pB = (const char*)lds + 32768 + (wc * 64 + lr) * 128;

  bf16x8 fXA[4], fXB[4], fYA[4], fYB[4];
  f32x4 acc[4][4] = {};

  // prologue: stage tiles 0,1 into buf 0,1; own t0 landed after VM(6);
  // barrier -> ALL waves' t0 landed; preload half1(t0) into fX.
  STAGE(0, 0);
  STAGE(1, 1);
  VM(6);
  SBAR;
  RD8(fXA, fXB, 0, kx0);
  LG(0); SCB;

  // kan segment: tiles 0..111
  for (int t = 0; t < 108; t += 3) {
    TILE(t,     0, 1, 2, 1, 1, VM(6));
    TILE(t + 1, 1, 2, 0, 1, 1, VM(6));
    TILE(t + 2, 2, 0, 1, 1, 1, VM(6));
  }
  TILE(108, 0, 1, 2, 1, 1, VM(6));
  TILE(109, 1, 2, 0, 1, 1, VM(6));
  TILE(110, 2, 0, 1, 1, 1, VM(6));
  TILE(111, 0, 1, 2, 1, 1, VM(6));

  // soft-threshold in-register at the kan/base boundary
#pragma unroll
  for (int i = 0; i < 4; ++i)
#pragma unroll
    for (int j = 0; j < 4; ++j)
#pragma unroll
      for (int e = 0; e < 4; ++e) {
        float v = acc[i][j][e];
        float a = fabsf(v) - thr;
        a = a > 0.f ? a : 0.f;
        acc[i][j][e] = v > 0.f ? a : -a;
      }

  // base segment: tiles 112..127
  for (int t = 112; t < 124; t += 3) {
    TILE(t,     1, 2, 0, 1, 1, VM(6));
    TILE(t + 1, 2, 0, 1, 1, 1, VM(6));
    TILE(t + 2, 0, 1, 2, 1, 1, VM(6));
  }
  TILE(124, 1, 2, 0, 1, 1, VM(6));
  TILE(125, 2, 0, 1, 1, 1, VM(6));   // stages tile 127 (last)
  TILE(126, 0, 1, 2, 0, 1, VM(0));   // no stage; drain so buf1(=t127) complete
  TILE(127, 1, 2, 0, 0, 0, (void)0); // no stage, no next-read

  // epilogue: out = (acc + bias) * oscale
  int rr = m0 + wr * 64 + ((l >> 4) << 2);
  int cc = n0 + wc * 64 + lr;
#pragma unroll
  for (int i = 0; i < 4; ++i)
#pragma unroll
    for (int j = 0; j < 4; ++j) {
      int c = cc + j * 16;
      float bc = bias[c];
#pragma unroll
      for (int e = 0; e < 4; ++e) {
        int r = rr + i * 16 + e;
        out[(size_t)r * OUTF + c] = (acc[i][j][e] + bc) * osc;
      }
    }
}

// ---------------------------------------------------------------------------
extern "C" void kernel_launch(void* const* d_in, const int* in_sizes, int n_in,
                              void* d_out, int out_size, void* d_ws, size_t ws_size,
                              hipStream_t stream) {
  const float* x              = (const float*)d_in[0];
  const float* base_w         = (const float*)d_in[1];
  const float* base_b         = (const float*)d_in[2];
  const float* u              = (const float*)d_in[3];
  const float* translation    = (const float*)d_in[4];
  const float* scale          = (const float*)d_in[5];
  const float* wavelet_w      = (const float*)d_in[6];
  const float* soft_threshold = (const float*)d_in[7];
  const float* output_scale   = (const float*)d_in[8];
  float* out = (float*)d_out;

  char* ws = (char*)d_ws;
  float* t_vec = (float*)ws;                                 // 1024 f32
  float* s_vec = t_vec + 1024;                               // 1024 f32
  float* scal  = s_vec + 1024;                               // 32 f32
  unsigned short* Wp = (unsigned short*)(ws + 16384);        // 16 MB
  char* dynbuf = ws + 16384 + (size_t)KTOT * OUTF * 2;

  size_t fixed = 16384 + (size_t)KTOT * OUTF * 2;
  size_t avail = ws_size > fixed ? ws_size - fixed : 0;

  const size_t ROW = (size_t)KTOT * 2;      // A' bytes per row
  size_t total = (size_t)NROWS * ROW;
  int nch = (int)((total + (avail > 0 ? avail : 1) - 1) / (avail > 0 ? avail : 1));
  if (nch < 1) nch = 1;
  long mc = (((NROWS + nch - 1) / nch) + 255) & ~255L;
  while (mc > 256 && (size_t)mc * ROW > avail) mc -= 256;
  if (mc < 256) mc = 256;   // assume ws >= ~21 MB

  unsigned short* Ap = (unsigned short*)dynbuf;

  // node 1: zero t (atomic accumulator)
  hipMemsetAsync(t_vec, 0, 1024 * sizeof(float), stream);
  // node 2: fused wtu_acc | wkan_cast | expand(chunk0)
  long nr0 = (NROWS < mc) ? NROWS : mc;
  prep_fused<<<3136, 256, 0, stream>>>(base_w, u, t_vec, wavelet_w, Wp,
                                       x, translation, scale, Ap, (int)nr0);
  // nodes 3-5: sigma chain + base-W cast
  mv_w_t<<<1024, 256, 0, stream>>>(base_w, t_vec, s_vec);
  sigma_finish<<<1, 256, 0, stream>>>(t_vec, s_vec, soft_threshold, output_scale, scal);
  wsn_cast<<<512, 256, 0, stream>>>(base_w, scal, Wp);

  // chunk loop: gemm(ci); expand(c(i+1))
  for (long r0 = 0; r0 < NROWS; r0 += mc) {
    long nr = (NROWS - r0 < mc) ? (NROWS - r0) : mc;
    if (r0 > 0)
      expand_kernel<<<2048, 256, 0, stream>>>(x, translation, scale, Ap,
                                              (int)r0, (int)nr);
    int mt = (int)(nr / 256);
    gemm_k<<<mt * 8, 512, 0, stream>>>(Ap, Wp, base_b, scal, out + (size_t)r0 * OUTF);
  }
}